// Round 3
// baseline (849.357 us; speedup 1.0000x reference)
//
#include <hip/hip_runtime.h>
#include <hip/hip_bf16.h>
#include <math.h>

// Problem constants (B,S,H,F,E,K) = (2,2048,1024,2048,8,2)
#define T_TOK 4096
#define HDIM  1024
#define FDIM  2048
#define EDIM  8
#define TKROW 8192   // T*K
#define N2F   4096   // 2F
#define MAX_SLOTS 80 // >= sum ceil(c_e/128) <= 64+8 = 72

typedef __attribute__((ext_vector_type(8))) short short8;
typedef __attribute__((ext_vector_type(4))) float f32x4;

__device__ __forceinline__ unsigned short f32_to_bf16(float f) {
  unsigned int u = __float_as_uint(f);
  u += 0x7FFFu + ((u >> 16) & 1u);   // round-to-nearest-even
  return (unsigned short)(u >> 16);
}

// ---------------- transpose+convert: [z][R][C] f32 -> [z][C][R] bf16 ----------------
__global__ void transpose_conv_kernel(const float* __restrict__ in,
                                      unsigned short* __restrict__ out,
                                      int R, int C) {
  __shared__ float tile[64][65];
  long base = (long)blockIdx.z * (long)R * (long)C;
  int c0 = blockIdx.x * 64, r0 = blockIdx.y * 64;
  int tx = (threadIdx.x & 15) * 4;
  int ty = threadIdx.x >> 4;
  #pragma unroll
  for (int j = 0; j < 64; j += 16) {
    int r = r0 + ty + j;
    float4 v = *(const float4*)&in[base + (long)r * C + c0 + tx];
    tile[ty + j][tx] = v.x; tile[ty + j][tx + 1] = v.y;
    tile[ty + j][tx + 2] = v.z; tile[ty + j][tx + 3] = v.w;
  }
  __syncthreads();
  int tx2 = threadIdx.x & 63, ty2 = threadIdx.x >> 6;
  #pragma unroll
  for (int j = 0; j < 64; j += 4) {
    int oc = ty2 + j;
    out[base + (long)(c0 + oc) * R + r0 + tx2] = f32_to_bf16(tile[tx2][oc]);
  }
}

// ---------------- router ----------------
__global__ void router_kernel(const float* __restrict__ x,
                              const float* __restrict__ wr,
                              int* __restrict__ eid, float* __restrict__ tgate,
                              float* __restrict__ p_sum,
                              float* __restrict__ lse2_sum,
                              int* __restrict__ counts) {
  __shared__ float s_p[EDIM];
  __shared__ float s_lse2;
  __shared__ int s_cnt[EDIM];
  if (threadIdx.x < EDIM) { s_p[threadIdx.x] = 0.f; s_cnt[threadIdx.x] = 0; }
  if (threadIdx.x == 0) s_lse2 = 0.f;
  __syncthreads();

  int wave = threadIdx.x >> 6;
  int lane = threadIdx.x & 63;

  for (int it = 0; it < 4; ++it) {
    int t = (blockIdx.x * 4 + wave) + it * 1024;
    float acc[EDIM];
    #pragma unroll
    for (int e = 0; e < EDIM; e++) acc[e] = 0.f;
    const float* xr = x + (long)t * HDIM;
    for (int h = lane; h < HDIM; h += 64) {
      float xv = xr[h];
      const float* w = wr + h * EDIM;
      #pragma unroll
      for (int e = 0; e < EDIM; e++) acc[e] += xv * w[e];
    }
    #pragma unroll
    for (int e = 0; e < EDIM; e++) {
      float v = acc[e];
      for (int off = 32; off > 0; off >>= 1) v += __shfl_down(v, off);
      acc[e] = v;
    }
    if (lane == 0) {
      float m = acc[0];
      #pragma unroll
      for (int e = 1; e < EDIM; e++) m = fmaxf(m, acc[e]);
      float ex[EDIM]; float se = 0.f;
      #pragma unroll
      for (int e = 0; e < EDIM; e++) { ex[e] = __expf(acc[e] - m); se += ex[e]; }
      float lse = m + __logf(se);
      atomicAdd(&s_lse2, lse * lse);
      float inv = 1.f / se;
      #pragma unroll
      for (int e = 0; e < EDIM; e++) atomicAdd(&s_p[e], ex[e] * inv);
      int i1 = 0;
      #pragma unroll
      for (int e = 1; e < EDIM; e++) if (acc[e] > acc[i1]) i1 = e;
      int i2 = (i1 == 0) ? 1 : 0;
      #pragma unroll
      for (int e = 0; e < EDIM; e++) if (e != i1 && acc[e] > acc[i2]) i2 = e;
      float g1 = 1.f / (1.f + __expf(acc[i2] - acc[i1]));
      eid[t * 2] = i1; eid[t * 2 + 1] = i2;
      tgate[t * 2] = g1; tgate[t * 2 + 1] = 1.f - g1;
      atomicAdd(&s_cnt[i1], 1); atomicAdd(&s_cnt[i2], 1);
    }
  }
  __syncthreads();
  if (threadIdx.x < EDIM) {
    atomicAdd(&p_sum[threadIdx.x], s_p[threadIdx.x]);
    atomicAdd(&counts[threadIdx.x], s_cnt[threadIdx.x]);
  }
  if (threadIdx.x == 0) atomicAdd(lse2_sum, s_lse2);
}

// ---------------- scan (1 thread): slots at 128-row granularity ----------------
__global__ void scan_kernel(const int* __restrict__ counts,
                            int* __restrict__ offsets, int* __restrict__ slot_e,
                            int* __restrict__ slot_m0, int* __restrict__ slot_rows,
                            int* __restrict__ n_slots, int* __restrict__ cursors) {
  int off = 0, s = 0;
  for (int e = 0; e < EDIM; e++) {
    offsets[e] = off;
    cursors[e] = 0;
    int c = counts[e];
    for (int m0 = 0; m0 < c; m0 += 128) {
      slot_e[s] = e; slot_m0[s] = off + m0;
      slot_rows[s] = min(128, c - m0); s++;
    }
    off += c;
  }
  *n_slots = s;
}

// ---------------- scatter (block-aggregated) ----------------
__global__ void scatter_kernel(const int* __restrict__ eid,
                               const float* __restrict__ tgate,
                               const int* __restrict__ offsets,
                               int* __restrict__ cursors,
                               int* __restrict__ btok, float* __restrict__ bgate) {
  __shared__ int lcnt[EDIM];
  __shared__ int lbase[EDIM];
  int tid = threadIdx.x;
  if (tid < EDIM) lcnt[tid] = 0;
  __syncthreads();
  int t = blockIdx.x * 256 + tid;
  int e0 = eid[t * 2], e1 = eid[t * 2 + 1];
  int p0 = atomicAdd(&lcnt[e0], 1);
  int p1 = atomicAdd(&lcnt[e1], 1);
  __syncthreads();
  if (tid < EDIM) lbase[tid] = atomicAdd(&cursors[tid], lcnt[tid]);
  __syncthreads();
  int r0 = offsets[e0] + lbase[e0] + p0;
  int r1 = offsets[e1] + lbase[e1] + p1;
  btok[r0] = t; bgate[r0] = tgate[t * 2];
  btok[r1] = t; bgate[r1] = tgate[t * 2 + 1];
}

// ---------------- gather bucketed X rows (fp32 -> bf16) ----------------
// block per bucket row: coalesced 4 KB read, 2 KB write
__global__ void gather_x_kernel(const float* __restrict__ x,
                                const int* __restrict__ btok,
                                unsigned short* __restrict__ xg) {
  int row = blockIdx.x;
  int tok = btok[row];
  const float* src = x + (long)tok * HDIM + threadIdx.x * 4;
  float4 v = *(const float4*)src;
  ushort4 o;
  o.x = f32_to_bf16(v.x); o.y = f32_to_bf16(v.y);
  o.z = f32_to_bf16(v.z); o.w = f32_to_bf16(v.w);
  *(ushort4*)(xg + (long)row * HDIM + threadIdx.x * 4) = o;
}

// ---------------- bias init ----------------
__global__ void bias_init_kernel(float* __restrict__ y,
                                 const float* __restrict__ bias, int n) {
  int i = blockIdx.x * blockDim.x + threadIdx.x;
  if (i < n) y[i] = bias[i & (HDIM - 1)];
}

// ---------------- GEMM1 (no-LDS, barrier-free): glu = GLU(Xg @ w_in[e]) ----------------
// block = 128 rows x 64 GLU cols (64 a-rows + 64 g-rows of B), per wave 64x(16a+16g)x2.
// Fragments loaded straight global->VGPR (16 B/lane), register prefetch distance 1.
__global__ __launch_bounds__(256) void gemm1_kernel(
    const unsigned short* __restrict__ xg,      // [TK+pad][H] bf16 (bucket order)
    const unsigned short* __restrict__ w_inT,   // [E][2F][H] bf16
    const int* __restrict__ slot_e, const int* __restrict__ slot_m0,
    const int* __restrict__ slot_rows, const int* __restrict__ n_slots,
    unsigned short* __restrict__ glu)           // [TK+pad][F] bf16
{
  int slot = blockIdx.x;
  if (slot >= *n_slots) return;
  int e = slot_e[slot], r0 = slot_m0[slot], nrows = slot_rows[slot];
  int c0 = blockIdx.y * 64;

  int tid = threadIdx.x;
  int wv = tid >> 6, lane = tid & 63;
  int wm = (wv & 1) * 64;       // wave row base
  int wn = (wv >> 1) * 32;      // wave col base within the 64 GLU cols
  int lm = lane & 15, kq = lane >> 4;

  const unsigned short* pa0 = xg + (long)(r0 + wm + lm) * HDIM + kq * 8;
  const unsigned short* wb = w_inT + (long)e * N2F * HDIM + kq * 8;
  const unsigned short* pb0 = wb + (long)(c0 + wn + lm) * HDIM;         // a rows
  const unsigned short* pb2 = wb + (long)(FDIM + c0 + wn + lm) * HDIM;  // g rows

  const unsigned short* pa[4];
  const unsigned short* pb[4];
  #pragma unroll
  for (int mi = 0; mi < 4; mi++) pa[mi] = pa0 + (long)mi * 16 * HDIM;
  pb[0] = pb0; pb[1] = pb0 + 16 * HDIM;
  pb[2] = pb2; pb[3] = pb2 + 16 * HDIM;

  f32x4 acc[4][4];
  #pragma unroll
  for (int i = 0; i < 4; i++)
    #pragma unroll
    for (int j = 0; j < 4; j++) acc[i][j] = (f32x4){0.f, 0.f, 0.f, 0.f};

  short8 af[4], bf[4];
  #pragma unroll
  for (int mi = 0; mi < 4; mi++) af[mi] = *(const short8*)(pa[mi]);
  #pragma unroll
  for (int ni = 0; ni < 4; ni++) bf[ni] = *(const short8*)(pb[ni]);

  #pragma unroll 2
  for (int k0 = 0; k0 < HDIM; k0 += 32) {
    int kn = (k0 + 32 < HDIM) ? (k0 + 32) : 0;   // last-iter prefetch harmless
    short8 a2[4], b2[4];
    #pragma unroll
    for (int mi = 0; mi < 4; mi++) a2[mi] = *(const short8*)(pa[mi] + kn);
    #pragma unroll
    for (int ni = 0; ni < 4; ni++) b2[ni] = *(const short8*)(pb[ni] + kn);
    #pragma unroll
    for (int mi = 0; mi < 4; mi++)
      #pragma unroll
      for (int ni = 0; ni < 4; ni++)
        acc[mi][ni] = __builtin_amdgcn_mfma_f32_16x16x32_bf16(af[mi], bf[ni], acc[mi][ni], 0, 0, 0);
    #pragma unroll
    for (int mi = 0; mi < 4; mi++) af[mi] = a2[mi];
    #pragma unroll
    for (int ni = 0; ni < 4; ni++) bf[ni] = b2[ni];
  }

  // epilogue: a = acc[mi][ni], g = acc[mi][ni+2], ni in 0..1
  #pragma unroll
  for (int mi = 0; mi < 4; mi++) {
    #pragma unroll
    for (int rr = 0; rr < 4; rr++) {
      int row = wm + mi * 16 + kq * 4 + rr;
      if (row < nrows) {
        #pragma unroll
        for (int ni = 0; ni < 2; ni++) {
          float a = acc[mi][ni][rr];
          float g = acc[mi][ni + 2][rr];
          float val = (a / (1.f + __expf(-a))) * g;   // silu(a)*g
          int col = c0 + wn + ni * 16 + lm;
          glu[(long)(r0 + row) * FDIM + col] = f32_to_bf16(val);
        }
      }
    }
  }
}

// ---------------- GEMM2 (no-LDS, barrier-free): y[tok] += gate*(glu @ w_out[e]) ----------------
// block = 128 rows x 64 cols; per wave 64x32; K=2048.
__global__ __launch_bounds__(256) void gemm2_kernel(
    const unsigned short* __restrict__ glu,     // [TK+pad][F] bf16 (bucket order)
    const unsigned short* __restrict__ w_outT,  // [E][H][F] bf16
    const int* __restrict__ btok, const float* __restrict__ bgate,
    const int* __restrict__ slot_e, const int* __restrict__ slot_m0,
    const int* __restrict__ slot_rows, const int* __restrict__ n_slots,
    float* __restrict__ y)
{
  int slot = blockIdx.x;
  if (slot >= *n_slots) return;
  int e = slot_e[slot], r0 = slot_m0[slot], nrows = slot_rows[slot];
  int c0 = blockIdx.y * 64;

  int tid = threadIdx.x;
  int wv = tid >> 6, lane = tid & 63;
  int wm = (wv & 1) * 64;
  int wn = (wv >> 1) * 32;
  int lm = lane & 15, kq = lane >> 4;

  const unsigned short* pa0 = glu + (long)(r0 + wm + lm) * FDIM + kq * 8;
  const unsigned short* pb0 =
      w_outT + (long)e * HDIM * FDIM + (long)(c0 + wn + lm) * FDIM + kq * 8;

  const unsigned short* pa[4];
  const unsigned short* pb[2];
  #pragma unroll
  for (int mi = 0; mi < 4; mi++) pa[mi] = pa0 + (long)mi * 16 * FDIM;
  pb[0] = pb0; pb[1] = pb0 + 16 * FDIM;

  f32x4 acc[4][2];
  #pragma unroll
  for (int i = 0; i < 4; i++)
    #pragma unroll
    for (int j = 0; j < 2; j++) acc[i][j] = (f32x4){0.f, 0.f, 0.f, 0.f};

  short8 af[4], bf[2];
  #pragma unroll
  for (int mi = 0; mi < 4; mi++) af[mi] = *(const short8*)(pa[mi]);
  #pragma unroll
  for (int ni = 0; ni < 2; ni++) bf[ni] = *(const short8*)(pb[ni]);

  #pragma unroll 2
  for (int k0 = 0; k0 < FDIM; k0 += 32) {
    int kn = (k0 + 32 < FDIM) ? (k0 + 32) : 0;
    short8 a2[4], b2[2];
    #pragma unroll
    for (int mi = 0; mi < 4; mi++) a2[mi] = *(const short8*)(pa[mi] + kn);
    #pragma unroll
    for (int ni = 0; ni < 2; ni++) b2[ni] = *(const short8*)(pb[ni] + kn);
    #pragma unroll
    for (int mi = 0; mi < 4; mi++)
      #pragma unroll
      for (int ni = 0; ni < 2; ni++)
        acc[mi][ni] = __builtin_amdgcn_mfma_f32_16x16x32_bf16(af[mi], bf[ni], acc[mi][ni], 0, 0, 0);
    #pragma unroll
    for (int mi = 0; mi < 4; mi++) af[mi] = a2[mi];
    #pragma unroll
    for (int ni = 0; ni < 2; ni++) bf[ni] = b2[ni];
  }

  #pragma unroll
  for (int mi = 0; mi < 4; mi++) {
    #pragma unroll
    for (int rr = 0; rr < 4; rr++) {
      int row = wm + mi * 16 + kq * 4 + rr;
      if (row < nrows) {
        int t = btok[r0 + row];
        float g = bgate[r0 + row];
        #pragma unroll
        for (int ni = 0; ni < 2; ni++) {
          int col = c0 + wn + ni * 16 + lm;
          atomicAdd(&y[(long)t * HDIM + col], acc[mi][ni][rr] * g);
        }
      }
    }
  }
}

// ---------------- finalize loss ----------------
__global__ void finalize_kernel(const float* __restrict__ p_sum,
                                const float* __restrict__ lse2,
                                const int* __restrict__ counts,
                                float* __restrict__ loss_out) {
  float P = 0.f;
  for (int e = 0; e < EDIM; e++) P += p_sum[e];
  float dot = 0.f;
  for (int e = 0; e < EDIM; e++)
    dot += (p_sum[e] / P) * ((float)counts[e] / (float)TKROW);
  *loss_out = (float)EDIM * dot + 0.1f * (*lse2) / (float)T_TOK;
}

// ---------------- host launch ----------------
extern "C" void kernel_launch(void* const* d_in, const int* in_sizes, int n_in,
                              void* d_out, int out_size, void* d_ws, size_t ws_size,
                              hipStream_t stream) {
  const float* x        = (const float*)d_in[0];
  const float* w_router = (const float*)d_in[1];
  const float* w_in     = (const float*)d_in[2];
  const float* w_out    = (const float*)d_in[3];
  const float* bias     = (const float*)d_in[4];
  float* y = (float*)d_out;                  // [T*H] then loss at [T*H]

  char* ws = (char*)d_ws;
  size_t o = 0;
  auto alloc = [&](size_t bytes) { size_t r = o; o = (o + bytes + 255) & ~(size_t)255; return r; };
  size_t o_meta    = alloc(256);
  size_t o_offsets = alloc(EDIM * 4);
  size_t o_slot_e  = alloc(MAX_SLOTS * 4);
  size_t o_slot_m0 = alloc(MAX_SLOTS * 4);
  size_t o_slot_nr = alloc(MAX_SLOTS * 4);
  size_t o_eid     = alloc((size_t)T_TOK * 2 * 4);
  size_t o_tgate   = alloc((size_t)T_TOK * 2 * 4);
  size_t o_btok    = alloc((size_t)(TKROW + 128) * 4);
  size_t o_bgate   = alloc((size_t)(TKROW + 128) * 4);
  size_t o_xg      = alloc((size_t)(TKROW + 128) * HDIM * 2);
  size_t o_winT    = alloc((size_t)EDIM * N2F * HDIM * 2);
  size_t o_woutT   = alloc((size_t)EDIM * HDIM * FDIM * 2);
  size_t o_glu     = alloc((size_t)(TKROW + 128) * FDIM * 2);
  (void)ws_size;

  float* p_sum   = (float*)(ws + o_meta);
  float* lse2    = (float*)(ws + o_meta + 32);
  int*   counts  = (int*)(ws + o_meta + 64);
  int*   cursors = (int*)(ws + o_meta + 96);
  int*   n_slots = (int*)(ws + o_meta + 128);
  int*   offsets = (int*)(ws + o_offsets);
  int*   slot_e  = (int*)(ws + o_slot_e);
  int*   slot_m0 = (int*)(ws + o_slot_m0);
  int*   slot_nr = (int*)(ws + o_slot_nr);
  int*   eid     = (int*)(ws + o_eid);
  float* tgate   = (float*)(ws + o_tgate);
  int*   btok    = (int*)(ws + o_btok);
  float* bgate   = (float*)(ws + o_bgate);
  unsigned short* xg    = (unsigned short*)(ws + o_xg);
  unsigned short* winT  = (unsigned short*)(ws + o_winT);
  unsigned short* woutT = (unsigned short*)(ws + o_woutT);
  unsigned short* glu   = (unsigned short*)(ws + o_glu);

  hipMemsetAsync(ws, 0, 256, stream);

  // weight transposes (fp32 -> bf16, K-contiguous rows)
  transpose_conv_kernel<<<dim3(N2F / 64, HDIM / 64, EDIM), dim3(256), 0, stream>>>(
      w_in, winT, HDIM, N2F);
  transpose_conv_kernel<<<dim3(HDIM / 64, FDIM / 64, EDIM), dim3(256), 0, stream>>>(
      w_out, woutT, FDIM, HDIM);

  // routing
  router_kernel<<<dim3(256), dim3(256), 0, stream>>>(
      x, w_router, eid, tgate, p_sum, lse2, counts);
  scan_kernel<<<dim3(1), dim3(1), 0, stream>>>(
      counts, offsets, slot_e, slot_m0, slot_nr, n_slots, cursors);
  scatter_kernel<<<dim3(T_TOK / 256), dim3(256), 0, stream>>>(
      eid, tgate, offsets, cursors, btok, bgate);

  // bucketed X (gather + bf16 convert)
  gather_x_kernel<<<dim3(TKROW), dim3(256), 0, stream>>>(x, btok, xg);

  // output init
  bias_init_kernel<<<dim3((T_TOK * HDIM) / 256), dim3(256), 0, stream>>>(
      y, bias, T_TOK * HDIM);

  // expert GEMMs (no-LDS, barrier-free)
  gemm1_kernel<<<dim3(MAX_SLOTS, FDIM / 64), dim3(256), 0, stream>>>(
      xg, winT, slot_e, slot_m0, slot_nr, n_slots, glu);
  gemm2_kernel<<<dim3(MAX_SLOTS, HDIM / 64), dim3(256), 0, stream>>>(
      glu, woutT, btok, bgate, slot_e, slot_m0, slot_nr, n_slots, y);

  // loss
  finalize_kernel<<<dim3(1), dim3(1), 0, stream>>>(
      p_sum, lse2, counts, y + (size_t)T_TOK * HDIM);
}

// Round 4
// 681.634 us; speedup vs baseline: 1.2461x; 1.2461x over previous
//
#include <hip/hip_runtime.h>
#include <hip/hip_bf16.h>
#include <math.h>

// Problem constants (B,S,H,F,E,K) = (2,2048,1024,2048,8,2)
#define T_TOK 4096
#define HDIM  1024
#define FDIM  2048
#define EDIM  8
#define TKROW 8192   // T*K
#define N2F   4096   // 2F

typedef __attribute__((ext_vector_type(8))) short short8;
typedef __attribute__((ext_vector_type(4))) float f32x4;

__device__ __forceinline__ unsigned short f32_to_bf16(float f) {
  unsigned int u = __float_as_uint(f);
  u += 0x7FFFu + ((u >> 16) & 1u);   // round-to-nearest-even
  return (unsigned short)(u >> 16);
}

__device__ __forceinline__ void gload_lds16(const void* g, void* l) {
  __builtin_amdgcn_global_load_lds(
      (const __attribute__((address_space(1))) unsigned int*)g,
      (__attribute__((address_space(3))) unsigned int*)l, 16, 0, 0);
}

// ---------------- transpose+convert: [z][R][C] f32 -> [z][C][R] bf16 ----------------
__global__ void transpose_conv_kernel(const float* __restrict__ in,
                                      unsigned short* __restrict__ out,
                                      int R, int C) {
  __shared__ float tile[64][65];
  long base = (long)blockIdx.z * (long)R * (long)C;
  int c0 = blockIdx.x * 64, r0 = blockIdx.y * 64;
  int tx = (threadIdx.x & 15) * 4;
  int ty = threadIdx.x >> 4;
  #pragma unroll
  for (int j = 0; j < 64; j += 16) {
    int r = r0 + ty + j;
    float4 v = *(const float4*)&in[base + (long)r * C + c0 + tx];
    tile[ty + j][tx] = v.x; tile[ty + j][tx + 1] = v.y;
    tile[ty + j][tx + 2] = v.z; tile[ty + j][tx + 3] = v.w;
  }
  __syncthreads();
  int tx2 = threadIdx.x & 63, ty2 = threadIdx.x >> 6;
  #pragma unroll
  for (int j = 0; j < 64; j += 4) {
    int oc = ty2 + j;
    out[base + (long)(c0 + oc) * R + r0 + tx2] = f32_to_bf16(tile[tx2][oc]);
  }
}

// ---------------- router ----------------
__global__ void router_kernel(const float* __restrict__ x,
                              const float* __restrict__ wr,
                              int* __restrict__ eid, float* __restrict__ tgate,
                              float* __restrict__ p_sum,
                              float* __restrict__ lse2_sum,
                              int* __restrict__ counts) {
  __shared__ float s_p[EDIM];
  __shared__ float s_lse2;
  __shared__ int s_cnt[EDIM];
  if (threadIdx.x < EDIM) { s_p[threadIdx.x] = 0.f; s_cnt[threadIdx.x] = 0; }
  if (threadIdx.x == 0) s_lse2 = 0.f;
  __syncthreads();

  int wave = threadIdx.x >> 6;
  int lane = threadIdx.x & 63;

  for (int it = 0; it < 4; ++it) {
    int t = (blockIdx.x * 4 + wave) + it * 1024;
    float acc[EDIM];
    #pragma unroll
    for (int e = 0; e < EDIM; e++) acc[e] = 0.f;
    const float* xr = x + (long)t * HDIM;
    for (int h = lane; h < HDIM; h += 64) {
      float xv = xr[h];
      const float* w = wr + h * EDIM;
      #pragma unroll
      for (int e = 0; e < EDIM; e++) acc[e] += xv * w[e];
    }
    #pragma unroll
    for (int e = 0; e < EDIM; e++) {
      float v = acc[e];
      for (int off = 32; off > 0; off >>= 1) v += __shfl_down(v, off);
      acc[e] = v;
    }
    if (lane == 0) {
      float m = acc[0];
      #pragma unroll
      for (int e = 1; e < EDIM; e++) m = fmaxf(m, acc[e]);
      float ex[EDIM]; float se = 0.f;
      #pragma unroll
      for (int e = 0; e < EDIM; e++) { ex[e] = __expf(acc[e] - m); se += ex[e]; }
      float lse = m + __logf(se);
      atomicAdd(&s_lse2, lse * lse);
      float inv = 1.f / se;
      #pragma unroll
      for (int e = 0; e < EDIM; e++) atomicAdd(&s_p[e], ex[e] * inv);
      int i1 = 0;
      #pragma unroll
      for (int e = 1; e < EDIM; e++) if (acc[e] > acc[i1]) i1 = e;
      int i2 = (i1 == 0) ? 1 : 0;
      #pragma unroll
      for (int e = 0; e < EDIM; e++) if (e != i1 && acc[e] > acc[i2]) i2 = e;
      float g1 = 1.f / (1.f + __expf(acc[i2] - acc[i1]));
      eid[t * 2] = i1; eid[t * 2 + 1] = i2;
      tgate[t * 2] = g1; tgate[t * 2 + 1] = 1.f - g1;
      atomicAdd(&s_cnt[i1], 1); atomicAdd(&s_cnt[i2], 1);
    }
  }
  __syncthreads();
  if (threadIdx.x < EDIM) {
    atomicAdd(&p_sum[threadIdx.x], s_p[threadIdx.x]);
    atomicAdd(&counts[threadIdx.x], s_cnt[threadIdx.x]);
  }
  if (threadIdx.x == 0) atomicAdd(lse2_sum, s_lse2);
}

// ---------------- scan (1 thread): prefix offsets ----------------
__global__ void scan_kernel(const int* __restrict__ counts,
                            int* __restrict__ offsets, int* __restrict__ cursors) {
  int off = 0;
  for (int e = 0; e < EDIM; e++) {
    offsets[e] = off; cursors[e] = 0;
    off += counts[e];
  }
}

// ---------------- scatter (block-aggregated) ----------------
__global__ void scatter_kernel(const int* __restrict__ eid,
                               const float* __restrict__ tgate,
                               const int* __restrict__ offsets,
                               int* __restrict__ cursors,
                               int* __restrict__ btok, float* __restrict__ bgate) {
  __shared__ int lcnt[EDIM];
  __shared__ int lbase[EDIM];
  int tid = threadIdx.x;
  if (tid < EDIM) lcnt[tid] = 0;
  __syncthreads();
  int t = blockIdx.x * 256 + tid;
  int e0 = eid[t * 2], e1 = eid[t * 2 + 1];
  int p0 = atomicAdd(&lcnt[e0], 1);
  int p1 = atomicAdd(&lcnt[e1], 1);
  __syncthreads();
  if (tid < EDIM) lbase[tid] = atomicAdd(&cursors[tid], lcnt[tid]);
  __syncthreads();
  int r0 = offsets[e0] + lbase[e0] + p0;
  int r1 = offsets[e1] + lbase[e1] + p1;
  btok[r0] = t; bgate[r0] = tgate[t * 2];
  btok[r1] = t; bgate[r1] = tgate[t * 2 + 1];
}

// ---------------- gather bucketed X rows (fp32 -> bf16) ----------------
__global__ void gather_x_kernel(const float* __restrict__ x,
                                const int* __restrict__ btok,
                                unsigned short* __restrict__ xg) {
  int row = blockIdx.x;
  int tok = btok[row];
  const float* src = x + (long)tok * HDIM + threadIdx.x * 4;
  float4 v = *(const float4*)src;
  ushort4 o;
  o.x = f32_to_bf16(v.x); o.y = f32_to_bf16(v.y);
  o.z = f32_to_bf16(v.z); o.w = f32_to_bf16(v.w);
  *(ushort4*)(xg + (long)row * HDIM + threadIdx.x * 4) = o;
}

// ---------------- bias init ----------------
__global__ void bias_init_kernel(float* __restrict__ y,
                                 const float* __restrict__ bias, int n) {
  int i = blockIdx.x * blockDim.x + threadIdx.x;
  if (i < n) y[i] = bias[i & (HDIM - 1)];
}

// ---------------- GEMM1 (m97-mini): glu = GLU(Xg @ w_in[e]) ----------------
// expert = blockIdx & 7 == XCD (bid%8 dispatch, m09). Block tile: M=64 x 64 GLU
// cols (128 B-rows: 64 a + 64 g). BK=64, 16 K-iters. LDS 24 KB chunk-major:
// A: [c0..7][row0..63][16B], B: [c0..7][brow0..127][16B]; staged via
// global_load_lds width=16, wave-uniform base + lane*16. Wave = 32M x 32GLU,
// acc[2][4] = 32 AGPR. Per-XCD ordering: slot inner, y outer -> A-slice L2-resident,
// B streamed once (8 MB/XCD compulsory).
__global__ __launch_bounds__(256, 4) void gemm1_kernel(
    const unsigned short* __restrict__ xg,      // [TK+pad][H] bf16 (bucket order)
    const unsigned short* __restrict__ w_inT,   // [E][2F][H] bf16
    const int* __restrict__ counts, const int* __restrict__ offsets,
    unsigned short* __restrict__ glu)           // [TK+pad][F] bf16
{
  int gid = blockIdx.x;
  int e = gid & 7;
  int j = gid >> 3;
  int sl = j & 31;          // slot inner (A reuse across y in L2)
  int y = j >> 5;           // 0..31
  int rem = counts[e] - sl * 64;
  if (rem <= 0) return;
  int nrows = rem < 64 ? rem : 64;
  int r0 = offsets[e] + sl * 64;
  int c0 = y * 64;

  __shared__ char lds[24576];
  char* ldsA = lds;             // 8 KB
  char* ldsB = lds + 8192;      // 16 KB

  int tid = threadIdx.x;
  // staging source addresses
  int arow = tid & 63, ac = tid >> 6;
  const char* ga = (const char*)(xg + (long)(r0 + arow) * HDIM) + ac * 16;
  int brow = tid & 127, bc = tid >> 7;
  int wrow = (brow < 64) ? (c0 + brow) : (FDIM + c0 + brow - 64);
  const char* gb = (const char*)(w_inT + (long)e * N2F * HDIM + (long)wrow * HDIM) + bc * 16;

  int lane = tid & 63, wv = tid >> 6;
  int lm = lane & 15, kq = lane >> 4;
  int wm = (wv & 1) * 32, wn = (wv >> 1) * 32;

  const char* pA = ldsA + kq * 1024 + (wm + lm) * 16;   // + mi*256 + s*4096
  const char* pB = ldsB + kq * 2048 + (wn + lm) * 16;   // + ni*256 + s*8192; g-half +1024

  f32x4 acc[2][4];
  #pragma unroll
  for (int i = 0; i < 2; i++)
    #pragma unroll
    for (int n = 0; n < 4; n++) acc[i][n] = (f32x4){0.f, 0.f, 0.f, 0.f};

  for (int kk = 0; kk < HDIM / 64; kk++) {
    long kb = (long)kk * 128;   // 64 k * 2 B
    gload_lds16(ga + kb,        ldsA + tid * 16);
    gload_lds16(ga + kb + 64,   ldsA + 4096 + tid * 16);
    gload_lds16(gb + kb,        ldsB + tid * 16);
    gload_lds16(gb + kb + 32,   ldsB + 4096 + tid * 16);
    gload_lds16(gb + kb + 64,   ldsB + 8192 + tid * 16);
    gload_lds16(gb + kb + 96,   ldsB + 12288 + tid * 16);
    __syncthreads();
    #pragma unroll
    for (int s = 0; s < 2; s++) {
      short8 a0 = *(const short8*)(pA + s * 4096);
      short8 a1 = *(const short8*)(pA + s * 4096 + 256);
      short8 b0 = *(const short8*)(pB + s * 8192);
      short8 b1 = *(const short8*)(pB + s * 8192 + 256);
      short8 b2 = *(const short8*)(pB + s * 8192 + 1024);
      short8 b3 = *(const short8*)(pB + s * 8192 + 1280);
      acc[0][0] = __builtin_amdgcn_mfma_f32_16x16x32_bf16(a0, b0, acc[0][0], 0, 0, 0);
      acc[0][1] = __builtin_amdgcn_mfma_f32_16x16x32_bf16(a0, b1, acc[0][1], 0, 0, 0);
      acc[0][2] = __builtin_amdgcn_mfma_f32_16x16x32_bf16(a0, b2, acc[0][2], 0, 0, 0);
      acc[0][3] = __builtin_amdgcn_mfma_f32_16x16x32_bf16(a0, b3, acc[0][3], 0, 0, 0);
      acc[1][0] = __builtin_amdgcn_mfma_f32_16x16x32_bf16(a1, b0, acc[1][0], 0, 0, 0);
      acc[1][1] = __builtin_amdgcn_mfma_f32_16x16x32_bf16(a1, b1, acc[1][1], 0, 0, 0);
      acc[1][2] = __builtin_amdgcn_mfma_f32_16x16x32_bf16(a1, b2, acc[1][2], 0, 0, 0);
      acc[1][3] = __builtin_amdgcn_mfma_f32_16x16x32_bf16(a1, b3, acc[1][3], 0, 0, 0);
    }
    __syncthreads();
  }

  // epilogue: a = acc[mi][ni], g = acc[mi][ni+2]
  #pragma unroll
  for (int mi = 0; mi < 2; mi++) {
    #pragma unroll
    for (int rr = 0; rr < 4; rr++) {
      int row = wm + mi * 16 + kq * 4 + rr;
      if (row < nrows) {
        #pragma unroll
        for (int ni = 0; ni < 2; ni++) {
          float a = acc[mi][ni][rr];
          float g = acc[mi][ni + 2][rr];
          float val = (a / (1.f + __expf(-a))) * g;   // silu(a)*g
          glu[(long)(r0 + row) * FDIM + c0 + wn + ni * 16 + lm] = f32_to_bf16(val);
        }
      }
    }
  }
}

// ---------------- GEMM2 (m97-mini): y[tok] += gate * (glu @ w_out[e]) ----------------
// Block tile: M=64 x N=128, BK=64, K=2048 (32 iters). Per-XCD ordering: y inner,
// slot outer -> B (4 MB/expert) L2-resident, A streamed once.
__global__ __launch_bounds__(256, 4) void gemm2_kernel(
    const unsigned short* __restrict__ glu,     // [TK+pad][F] bf16 (bucket order)
    const unsigned short* __restrict__ w_outT,  // [E][H][F] bf16
    const int* __restrict__ counts, const int* __restrict__ offsets,
    const int* __restrict__ btok, const float* __restrict__ bgate,
    float* __restrict__ y)
{
  int gid = blockIdx.x;
  int e = gid & 7;
  int j = gid >> 3;
  int yb = j & 7;           // y inner (B reuse across slots in L2)
  int sl = j >> 3;          // 0..31
  int rem = counts[e] - sl * 64;
  if (rem <= 0) return;
  int nrows = rem < 64 ? rem : 64;
  int r0 = offsets[e] + sl * 64;
  int c0 = yb * 128;

  __shared__ char lds[24576];
  char* ldsA = lds;             // 8 KB
  char* ldsB = lds + 8192;      // 16 KB

  int tid = threadIdx.x;
  int arow = tid & 63, ac = tid >> 6;
  const char* ga = (const char*)(glu + (long)(r0 + arow) * FDIM) + ac * 16;
  int brow = tid & 127, bc = tid >> 7;
  const char* gb = (const char*)(w_outT + (long)e * HDIM * FDIM + (long)(c0 + brow) * FDIM) + bc * 16;

  int lane = tid & 63, wv = tid >> 6;
  int lm = lane & 15, kq = lane >> 4;
  int wm = (wv & 1) * 32, wn = (wv >> 1) * 64;

  const char* pA = ldsA + kq * 1024 + (wm + lm) * 16;   // + mi*256 + s*4096
  const char* pB = ldsB + kq * 2048 + (wn + lm) * 16;   // + ni*256 + s*8192

  f32x4 acc[2][4];
  #pragma unroll
  for (int i = 0; i < 2; i++)
    #pragma unroll
    for (int n = 0; n < 4; n++) acc[i][n] = (f32x4){0.f, 0.f, 0.f, 0.f};

  for (int kk = 0; kk < FDIM / 64; kk++) {
    long kb = (long)kk * 128;
    gload_lds16(ga + kb,        ldsA + tid * 16);
    gload_lds16(ga + kb + 64,   ldsA + 4096 + tid * 16);
    gload_lds16(gb + kb,        ldsB + tid * 16);
    gload_lds16(gb + kb + 32,   ldsB + 4096 + tid * 16);
    gload_lds16(gb + kb + 64,   ldsB + 8192 + tid * 16);
    gload_lds16(gb + kb + 96,   ldsB + 12288 + tid * 16);
    __syncthreads();
    #pragma unroll
    for (int s = 0; s < 2; s++) {
      short8 a0 = *(const short8*)(pA + s * 4096);
      short8 a1 = *(const short8*)(pA + s * 4096 + 256);
      short8 b0 = *(const short8*)(pB + s * 8192);
      short8 b1 = *(const short8*)(pB + s * 8192 + 256);
      short8 b2 = *(const short8*)(pB + s * 8192 + 512);
      short8 b3 = *(const short8*)(pB + s * 8192 + 768);
      acc[0][0] = __builtin_amdgcn_mfma_f32_16x16x32_bf16(a0, b0, acc[0][0], 0, 0, 0);
      acc[0][1] = __builtin_amdgcn_mfma_f32_16x16x32_bf16(a0, b1, acc[0][1], 0, 0, 0);
      acc[0][2] = __builtin_amdgcn_mfma_f32_16x16x32_bf16(a0, b2, acc[0][2], 0, 0, 0);
      acc[0][3] = __builtin_amdgcn_mfma_f32_16x16x32_bf16(a0, b3, acc[0][3], 0, 0, 0);
      acc[1][0] = __builtin_amdgcn_mfma_f32_16x16x32_bf16(a1, b0, acc[1][0], 0, 0, 0);
      acc[1][1] = __builtin_amdgcn_mfma_f32_16x16x32_bf16(a1, b1, acc[1][1], 0, 0, 0);
      acc[1][2] = __builtin_amdgcn_mfma_f32_16x16x32_bf16(a1, b2, acc[1][2], 0, 0, 0);
      acc[1][3] = __builtin_amdgcn_mfma_f32_16x16x32_bf16(a1, b3, acc[1][3], 0, 0, 0);
    }
    __syncthreads();
  }

  #pragma unroll
  for (int mi = 0; mi < 2; mi++) {
    #pragma unroll
    for (int rr = 0; rr < 4; rr++) {
      int row = wm + mi * 16 + kq * 4 + rr;
      if (row < nrows) {
        int t = btok[r0 + row];
        float g = bgate[r0 + row];
        #pragma unroll
        for (int ni = 0; ni < 4; ni++) {
          atomicAdd(&y[(long)t * HDIM + c0 + wn + ni * 16 + lm], acc[mi][ni][rr] * g);
        }
      }
    }
  }
}

// ---------------- finalize loss ----------------
__global__ void finalize_kernel(const float* __restrict__ p_sum,
                                const float* __restrict__ lse2,
                                const int* __restrict__ counts,
                                float* __restrict__ loss_out) {
  float P = 0.f;
  for (int e = 0; e < EDIM; e++) P += p_sum[e];
  float dot = 0.f;
  for (int e = 0; e < EDIM; e++)
    dot += (p_sum[e] / P) * ((float)counts[e] / (float)TKROW);
  *loss_out = (float)EDIM * dot + 0.1f * (*lse2) / (float)T_TOK;
}

// ---------------- host launch ----------------
extern "C" void kernel_launch(void* const* d_in, const int* in_sizes, int n_in,
                              void* d_out, int out_size, void* d_ws, size_t ws_size,
                              hipStream_t stream) {
  const float* x        = (const float*)d_in[0];
  const float* w_router = (const float*)d_in[1];
  const float* w_in     = (const float*)d_in[2];
  const float* w_out    = (const float*)d_in[3];
  const float* bias     = (const float*)d_in[4];
  float* y = (float*)d_out;                  // [T*H] then loss at [T*H]

  char* ws = (char*)d_ws;
  size_t o = 0;
  auto alloc = [&](size_t bytes) { size_t r = o; o = (o + bytes + 255) & ~(size_t)255; return r; };
  size_t o_meta    = alloc(256);
  size_t o_offsets = alloc(EDIM * 4);
  size_t o_eid     = alloc((size_t)T_TOK * 2 * 4);
  size_t o_tgate   = alloc((size_t)T_TOK * 2 * 4);
  size_t o_btok    = alloc((size_t)(TKROW + 128) * 4);
  size_t o_bgate   = alloc((size_t)(TKROW + 128) * 4);
  size_t o_xg      = alloc((size_t)(TKROW + 128) * HDIM * 2);
  size_t o_winT    = alloc((size_t)EDIM * N2F * HDIM * 2);
  size_t o_woutT   = alloc((size_t)EDIM * HDIM * FDIM * 2);
  size_t o_glu     = alloc((size_t)(TKROW + 128) * FDIM * 2);
  (void)ws_size;

  float* p_sum   = (float*)(ws + o_meta);
  float* lse2    = (float*)(ws + o_meta + 32);
  int*   counts  = (int*)(ws + o_meta + 64);
  int*   cursors = (int*)(ws + o_meta + 96);
  int*   offsets = (int*)(ws + o_offsets);
  int*   eid     = (int*)(ws + o_eid);
  float* tgate   = (float*)(ws + o_tgate);
  int*   btok    = (int*)(ws + o_btok);
  float* bgate   = (float*)(ws + o_bgate);
  unsigned short* xg    = (unsigned short*)(ws + o_xg);
  unsigned short* winT  = (unsigned short*)(ws + o_winT);
  unsigned short* woutT = (unsigned short*)(ws + o_woutT);
  unsigned short* glu   = (unsigned short*)(ws + o_glu);

  hipMemsetAsync(ws, 0, 256, stream);

  // weight transposes (fp32 -> bf16, K-contiguous rows)
  transpose_conv_kernel<<<dim3(N2F / 64, HDIM / 64, EDIM), dim3(256), 0, stream>>>(
      w_in, winT, HDIM, N2F);
  transpose_conv_kernel<<<dim3(HDIM / 64, FDIM / 64, EDIM), dim3(256), 0, stream>>>(
      w_out, woutT, FDIM, HDIM);

  // routing
  router_kernel<<<dim3(256), dim3(256), 0, stream>>>(
      x, w_router, eid, tgate, p_sum, lse2, counts);
  scan_kernel<<<dim3(1), dim3(1), 0, stream>>>(counts, offsets, cursors);
  scatter_kernel<<<dim3(T_TOK / 256), dim3(256), 0, stream>>>(
      eid, tgate, offsets, cursors, btok, bgate);

  // bucketed X (gather + bf16 convert)
  gather_x_kernel<<<dim3(TKROW), dim3(256), 0, stream>>>(x, btok, xg);

  // output init
  bias_init_kernel<<<dim3((T_TOK * HDIM) / 256), dim3(256), 0, stream>>>(
      y, bias, T_TOK * HDIM);

  // expert GEMMs: expert = bid&7 = XCD; 32 slot slots x (32|8) col tiles
  gemm1_kernel<<<dim3(8 * 32 * 32), dim3(256), 0, stream>>>(
      xg, winT, counts, offsets, glu);
  gemm2_kernel<<<dim3(8 * 32 * 8), dim3(256), 0, stream>>>(
      glu, woutT, counts, offsets, btok, bgate, y);

  // loss
  finalize_kernel<<<dim3(1), dim3(1), 0, stream>>>(
      p_sum, lse2, counts, y + (size_t)T_TOK * HDIM);
}